// Round 1
// baseline (1198.953 us; speedup 1.0000x reference)
//
#include <hip/hip_runtime.h>
#include <cstddef>

#define DIM 256
#define NSLOT 8
#define BATCH 64
#define NTOK 4096
#define SEG 32
#define ROWS_PER_BLK (NTOK / SEG) /* 128 */
#define ITERS 3
#define EPS 1e-5f

// ---------------- workspace layout (float offsets) ----------------
enum : size_t {
    OFF_M     = 0,                               // [256][256]  Wq^T Wk * scale
    OFF_WIHT  = OFF_M    + 256 * 256,            // [256][768]
    OFF_WHHT  = OFF_WIHT + 256 * 768,            // [256][768]
    OFF_WVT   = OFF_WHHT + 256 * 768,            // [256][256]
    OFF_W1T   = OFF_WVT  + 256 * 256,            // [256][256]
    OFF_W2T   = OFF_W1T  + 256 * 256,            // [256][256]
    OFF_SLOTS = OFF_W2T  + 256 * 256,            // [64][8][256]
    OFF_SNEW  = OFF_SLOTS + BATCH * NSLOT * 256, // [64][8][256]
    OFF_QT    = OFF_SNEW  + BATCH * NSLOT * 256, // [64][8][256]
    OFF_H     = OFF_QT    + BATCH * NSLOT * 256, // [64][8][256]
    OFF_UPD   = OFF_H     + BATCH * NSLOT * 256, // [64][8][256]
    OFF_UPART = OFF_UPD   + BATCH * NSLOT * 256, // [64][SEG][8][256]
    OFF_LPART = OFF_UPART + (size_t)BATCH * SEG * NSLOT * 256, // [64][SEG][8]
    WS_FLOATS = OFF_LPART + BATCH * SEG * NSLOT
};

// ---------------- weight transposes (coalesced via LDS tile) ----------------
__global__ __launch_bounds__(256) void k_transpose(const float* __restrict__ w_ih,
                                                   const float* __restrict__ w_hh,
                                                   const float* __restrict__ wv,
                                                   const float* __restrict__ w1,
                                                   const float* __restrict__ w2,
                                                   float* __restrict__ ws) {
    int z = blockIdx.z;
    const float* src;
    float* dst;
    int R;
    if (z == 0)      { src = w_ih; dst = ws + OFF_WIHT; R = 768; }
    else if (z == 1) { src = w_hh; dst = ws + OFF_WHHT; R = 768; }
    else if (z == 2) { src = wv;   dst = ws + OFF_WVT;  R = 256; }
    else if (z == 3) { src = w1;   dst = ws + OFF_W1T;  R = 256; }
    else             { src = w2;   dst = ws + OFF_W2T;  R = 256; }
    if ((int)blockIdx.x * 32 >= R) return;
    __shared__ float tile[32][33];
    int lx = threadIdx.x & 31, ly = threadIdx.x >> 5;
    int r0 = blockIdx.x * 32, c0 = blockIdx.y * 32;
#pragma unroll
    for (int p = 0; p < 4; ++p)
        tile[ly + p * 8][lx] = src[(size_t)(r0 + ly + p * 8) * 256 + c0 + lx];
    __syncthreads();
#pragma unroll
    for (int p = 0; p < 4; ++p)
        dst[(size_t)(c0 + ly + p * 8) * R + r0 + lx] = tile[lx][ly + p * 8];
}

// ---------------- M = (Wq^T @ Wk) * d^-0.5 ----------------
__global__ __launch_bounds__(256) void k_m(const float* __restrict__ wq,
                                           const float* __restrict__ wk,
                                           float* __restrict__ ws) {
    int d = blockIdx.x, t = threadIdx.x;
    float acc = 0.f;
    for (int e = 0; e < 256; ++e)
        acc += wq[e * 256 + d] * wk[e * 256 + t];
    ws[OFF_M + d * 256 + t] = acc * 0.0625f; // 256^-0.5
}

// ---------------- slots init ----------------
__global__ __launch_bounds__(256) void k_init(const float* __restrict__ mu,
                                              const float* __restrict__ logsig,
                                              const float* __restrict__ noise,
                                              float* __restrict__ ws) {
    int i = blockIdx.x * 256 + threadIdx.x; // grid 512 -> 131072
    int d = i & 255;
    ws[OFF_SLOTS + i] = mu[d] + noise[i] * __expf(logsig[d]);
}

// ---------------- qt = LN(slots, g_sl) @ M ----------------
__global__ __launch_bounds__(256) void k_qt(float* __restrict__ ws,
                                            const float* __restrict__ g_sl,
                                            const float* __restrict__ be_sl) {
    __shared__ float ln[2048];
    int chunk = blockIdx.x, b = blockIdx.y;
    int t = threadIdx.x, wave = t >> 6, lane = t & 63;
    const float* slots = ws + OFF_SLOTS + b * 2048;
    float4 gf = ((const float4*)g_sl)[lane];
    float4 bf = ((const float4*)be_sl)[lane];
#pragma unroll
    for (int rr = 0; rr < 2; ++rr) {
        int r = wave + rr * 4;
        float4 v = ((const float4*)(slots + r * 256))[lane];
        float s1 = v.x + v.y + v.z + v.w;
        float s2 = v.x * v.x + v.y * v.y + v.z * v.z + v.w * v.w;
#pragma unroll
        for (int m = 1; m < 64; m <<= 1) { s1 += __shfl_xor(s1, m); s2 += __shfl_xor(s2, m); }
        float mu = s1 * (1.f / 256.f);
        float rstd = rsqrtf(s2 * (1.f / 256.f) - mu * mu + EPS);
        float4 o;
        o.x = (v.x - mu) * rstd * gf.x + bf.x;
        o.y = (v.y - mu) * rstd * gf.y + bf.y;
        o.z = (v.z - mu) * rstd * gf.z + bf.z;
        o.w = (v.w - mu) * rstd * gf.w + bf.w;
        *((float4*)&ln[r * 256 + lane * 4]) = o;
    }
    __syncthreads();
    const float* M = ws + OFF_M;
    int k0 = t >> 6;               // wave-uniform
    int e = chunk * 64 + (t & 63);
    float a0 = 0.f, a1 = 0.f;
    for (int d = 0; d < 256; ++d) {
        float m = M[d * 256 + e];
        a0 += ln[k0 * 256 + d] * m;
        a1 += ln[(k0 + 4) * 256 + d] * m;
    }
    float* qt = ws + OFF_QT + b * 2048;
    qt[k0 * 256 + e] = a0;
    qt[(k0 + 4) * 256 + e] = a1;
}

// ---------------- flash-style attention pass over x ----------------
__global__ __launch_bounds__(64) void k_attn(const float* __restrict__ x,
                                             const float* __restrict__ g_in,
                                             const float* __restrict__ be_in,
                                             float* __restrict__ ws) {
    int seg = blockIdx.x, b = blockIdx.y;
    int lane = threadIdx.x;
    const float* qtg = ws + OFF_QT + b * 2048;
    float4 qf[8];
#pragma unroll
    for (int s = 0; s < 8; ++s) qf[s] = ((const float4*)qtg)[s * 64 + lane];
    float4 gf = ((const float4*)g_in)[lane];
    float4 bf = ((const float4*)be_in)[lane];
    const float4* xb = (const float4*)(x + (size_t)b * NTOK * 256) + (size_t)seg * ROWS_PER_BLK * 64;
    float4 U[8];
#pragma unroll
    for (int s = 0; s < 8; ++s) U[s] = make_float4(0.f, 0.f, 0.f, 0.f);
    float l[8] = {0.f, 0.f, 0.f, 0.f, 0.f, 0.f, 0.f, 0.f};
    float4 x0 = xb[lane];
    float4 x1 = xb[64 + lane];
    for (int r = 0; r < ROWS_PER_BLK; ++r) {
        int rn = (r + 2 < ROWS_PER_BLK) ? r + 2 : ROWS_PER_BLK - 1;
        float4 xn = xb[rn * 64 + lane];
        float4 xv = x0;
        // LayerNorm of the row
        float s1 = xv.x + xv.y + xv.z + xv.w;
        float s2 = xv.x * xv.x + xv.y * xv.y + xv.z * xv.z + xv.w * xv.w;
#pragma unroll
        for (int m = 1; m < 64; m <<= 1) { s1 += __shfl_xor(s1, m); s2 += __shfl_xor(s2, m); }
        float mu = s1 * (1.f / 256.f);
        float rstd = rsqrtf(s2 * (1.f / 256.f) - mu * mu + EPS);
        float4 xl;
        xl.x = (xv.x - mu) * rstd * gf.x + bf.x;
        xl.y = (xv.y - mu) * rstd * gf.y + bf.y;
        xl.z = (xv.z - mu) * rstd * gf.z + bf.z;
        xl.w = (xv.w - mu) * rstd * gf.w + bf.w;
        // 8 logit partials
        float p[8];
#pragma unroll
        for (int s = 0; s < 8; ++s)
            p[s] = xl.x * qf[s].x + xl.y * qf[s].y + xl.z * qf[s].z + xl.w * qf[s].w;
        // folded multi-value butterfly reduction: 8 values across 64 lanes
        int c0 = lane & 1, c1 = lane & 2, c2 = lane & 4;
        float q[4];
#pragma unroll
        for (int jj = 0; jj < 4; ++jj) {
            float send = c0 ? p[jj] : p[jj + 4];
            float recv = __shfl_xor(send, 1);
            q[jj] = (c0 ? p[jj + 4] : p[jj]) + recv;
        }
        float r2[2];
#pragma unroll
        for (int jj = 0; jj < 2; ++jj) {
            float send = c1 ? q[jj] : q[jj + 2];
            float recv = __shfl_xor(send, 2);
            r2[jj] = (c1 ? q[jj + 2] : q[jj]) + recv;
        }
        float send3 = c2 ? r2[0] : r2[1];
        float recv3 = __shfl_xor(send3, 4);
        float tt = (c2 ? r2[1] : r2[0]) + recv3;
        tt += __shfl_xor(tt, 8);
        tt += __shfl_xor(tt, 16);
        tt += __shfl_xor(tt, 32);
        // lane (b0,b1,b2) owns slot 4*b0+2*b1+b2 -> inverse map {0,4,2,6,1,5,3,7}
        float wv[8];
        wv[0] = __shfl(tt, 0); wv[1] = __shfl(tt, 4);
        wv[2] = __shfl(tt, 2); wv[3] = __shfl(tt, 6);
        wv[4] = __shfl(tt, 1); wv[5] = __shfl(tt, 5);
        wv[6] = __shfl(tt, 3); wv[7] = __shfl(tt, 7);
#pragma unroll
        for (int s = 0; s < 8; ++s) {
            float e = __expf(fminf(wv[s], 30.f)); // logits are small; no max-sub needed
            l[s] += e;
            U[s].x += e * xl.x; U[s].y += e * xl.y;
            U[s].z += e * xl.z; U[s].w += e * xl.w;
        }
        x0 = x1; x1 = xn;
    }
    float* Ub = ws + OFF_UPART + ((size_t)(b * SEG + seg) * 8) * 256;
#pragma unroll
    for (int s = 0; s < 8; ++s)
        ((float4*)(Ub + s * 256))[lane] = U[s];
    if (lane == 0) {
        float* Lb = ws + OFF_LPART + (b * SEG + seg) * 8;
#pragma unroll
        for (int s = 0; s < 8; ++s) Lb[s] = l[s];
    }
}

// ---------------- combine partials, updates = (U/l) @ Wv^T ----------------
__global__ __launch_bounds__(256) void k_upd(float* __restrict__ ws) {
    __shared__ float uc[2048];
    __shared__ float invl[8];
    int b = blockIdx.x, t = threadIdx.x;
    if (t < 8) {
        float ls = 0.f;
        for (int g = 0; g < SEG; ++g) ls += ws[OFF_LPART + (b * SEG + g) * 8 + t];
        invl[t] = 1.f / ls;
    }
    float acc[8] = {0.f, 0.f, 0.f, 0.f, 0.f, 0.f, 0.f, 0.f};
    const float* up0 = ws + OFF_UPART + (size_t)b * SEG * 8 * 256;
    for (int g = 0; g < SEG; ++g) {
        const float* up = up0 + g * 2048;
#pragma unroll
        for (int s = 0; s < 8; ++s) acc[s] += up[s * 256 + t];
    }
    __syncthreads();
#pragma unroll
    for (int s = 0; s < 8; ++s) uc[s * 256 + t] = acc[s] * invl[s];
    __syncthreads();
    const float* WvT = ws + OFF_WVT;
    int k0 = t >> 6;   // wave-uniform
    int e0 = t & 63;
    float o0[4] = {0.f, 0.f, 0.f, 0.f};
    float o1[4] = {0.f, 0.f, 0.f, 0.f};
    for (int d = 0; d < 256; ++d) {
        float u0 = uc[k0 * 256 + d], u1 = uc[(k0 + 4) * 256 + d];
#pragma unroll
        for (int c = 0; c < 4; ++c) {
            float w = WvT[d * 256 + c * 64 + e0];
            o0[c] += u0 * w;
            o1[c] += u1 * w;
        }
    }
    float* updg = ws + OFF_UPD + b * 2048;
#pragma unroll
    for (int c = 0; c < 4; ++c) {
        updg[k0 * 256 + c * 64 + e0] = o0[c];
        updg[(k0 + 4) * 256 + c * 64 + e0] = o1[c];
    }
}

// ---------------- GRU cell ----------------
__global__ __launch_bounds__(256) void k_gru(float* __restrict__ ws,
                                             const float* __restrict__ b_ih,
                                             const float* __restrict__ b_hh) {
    __shared__ float upd[2048], sl[2048];
    int cg = blockIdx.x, b = blockIdx.y, t = threadIdx.x;
    const float* updg = ws + OFF_UPD + b * 2048;
    const float* slg = ws + OFF_SLOTS + b * 2048;
#pragma unroll
    for (int j = 0; j < 8; ++j) {
        upd[j * 256 + t] = updg[j * 256 + t];
        sl[j * 256 + t] = slg[j * 256 + t];
    }
    __syncthreads();
    int k = t >> 5, j = t & 31, c = cg * 32 + j;
    const float* WihT = ws + OFF_WIHT;
    const float* WhhT = ws + OFF_WHHT;
    float ar = 0.f, az = 0.f, an = 0.f, hr = 0.f, hz = 0.f, hn = 0.f;
    for (int d = 0; d < 256; ++d) {
        float ud = upd[k * 256 + d], sd = sl[k * 256 + d];
        const float* wi = WihT + d * 768;
        const float* wh = WhhT + d * 768;
        ar += ud * wi[c];       az += ud * wi[256 + c]; an += ud * wi[512 + c];
        hr += sd * wh[c];       hz += sd * wh[256 + c]; hn += sd * wh[512 + c];
    }
    float rg = 1.f / (1.f + __expf(-(ar + b_ih[c] + hr + b_hh[c])));
    float zg = 1.f / (1.f + __expf(-(az + b_ih[256 + c] + hz + b_hh[256 + c])));
    float ng = tanhf(an + b_ih[512 + c] + rg * (hn + b_hh[512 + c]));
    float hval = sl[k * 256 + c];
    ws[OFF_SNEW + b * 2048 + k * 256 + c] = (1.f - zg) * ng + zg * hval;
}

// ---------------- h = relu(LN(snew, g_ff) @ W1^T + b1) ----------------
__global__ __launch_bounds__(256) void k_mlp1(float* __restrict__ ws,
                                              const float* __restrict__ g_ff,
                                              const float* __restrict__ be_ff,
                                              const float* __restrict__ b1v) {
    __shared__ float ln[2048];
    int chunk = blockIdx.x, b = blockIdx.y;
    int t = threadIdx.x, wave = t >> 6, lane = t & 63;
    const float* sn = ws + OFF_SNEW + b * 2048;
    float4 gf = ((const float4*)g_ff)[lane];
    float4 bf = ((const float4*)be_ff)[lane];
#pragma unroll
    for (int rr = 0; rr < 2; ++rr) {
        int r = wave + rr * 4;
        float4 v = ((const float4*)(sn + r * 256))[lane];
        float s1 = v.x + v.y + v.z + v.w;
        float s2 = v.x * v.x + v.y * v.y + v.z * v.z + v.w * v.w;
#pragma unroll
        for (int m = 1; m < 64; m <<= 1) { s1 += __shfl_xor(s1, m); s2 += __shfl_xor(s2, m); }
        float mu = s1 * (1.f / 256.f);
        float rstd = rsqrtf(s2 * (1.f / 256.f) - mu * mu + EPS);
        float4 o;
        o.x = (v.x - mu) * rstd * gf.x + bf.x;
        o.y = (v.y - mu) * rstd * gf.y + bf.y;
        o.z = (v.z - mu) * rstd * gf.z + bf.z;
        o.w = (v.w - mu) * rstd * gf.w + bf.w;
        *((float4*)&ln[r * 256 + lane * 4]) = o;
    }
    __syncthreads();
    const float* W1T = ws + OFF_W1T;
    int k0 = t >> 6, e = chunk * 64 + (t & 63);
    float a0 = 0.f, a1 = 0.f;
    for (int d = 0; d < 256; ++d) {
        float w = W1T[d * 256 + e];
        a0 += ln[k0 * 256 + d] * w;
        a1 += ln[(k0 + 4) * 256 + d] * w;
    }
    float* h = ws + OFF_H + b * 2048;
    float bb = b1v[e];
    h[k0 * 256 + e] = fmaxf(a0 + bb, 0.f);
    h[(k0 + 4) * 256 + e] = fmaxf(a1 + bb, 0.f);
}

// ---------------- slots = snew + h @ W2^T + b2 (optionally -> out) ----------------
__global__ __launch_bounds__(256) void k_mlp2(float* __restrict__ ws,
                                              const float* __restrict__ b2v,
                                              float* __restrict__ dout) {
    __shared__ float hl[2048];
    int chunk = blockIdx.x, b = blockIdx.y, t = threadIdx.x;
    const float* h = ws + OFF_H + b * 2048;
#pragma unroll
    for (int j = 0; j < 8; ++j) hl[j * 256 + t] = h[j * 256 + t];
    __syncthreads();
    int k0 = t >> 6, e = chunk * 64 + (t & 63);
    const float* W2T = ws + OFF_W2T;
    float a0 = 0.f, a1 = 0.f;
    for (int d = 0; d < 256; ++d) {
        float w = W2T[d * 256 + e];
        a0 += hl[k0 * 256 + d] * w;
        a1 += hl[(k0 + 4) * 256 + d] * w;
    }
    const float* sn = ws + OFF_SNEW + b * 2048;
    float bb = b2v[e];
    float out0 = sn[k0 * 256 + e] + a0 + bb;
    float out1 = sn[(k0 + 4) * 256 + e] + a1 + bb;
    float* sl = ws + OFF_SLOTS + b * 2048;
    sl[k0 * 256 + e] = out0;
    sl[(k0 + 4) * 256 + e] = out1;
    if (dout) {
        dout[b * 2048 + k0 * 256 + e] = out0;
        dout[b * 2048 + (k0 + 4) * 256 + e] = out1;
    }
}

extern "C" void kernel_launch(void* const* d_in, const int* in_sizes, int n_in,
                              void* d_out, int out_size, void* d_ws, size_t ws_size,
                              hipStream_t stream) {
    const float* x      = (const float*)d_in[0];
    const float* noise  = (const float*)d_in[1];
    const float* mu     = (const float*)d_in[2];
    const float* logsig = (const float*)d_in[3];
    const float* Wq     = (const float*)d_in[4];
    const float* Wk     = (const float*)d_in[5];
    const float* Wv     = (const float*)d_in[6];
    const float* W_ih   = (const float*)d_in[7];
    const float* W_hh   = (const float*)d_in[8];
    const float* b_ih   = (const float*)d_in[9];
    const float* b_hh   = (const float*)d_in[10];
    const float* W1     = (const float*)d_in[11];
    const float* b1     = (const float*)d_in[12];
    const float* W2     = (const float*)d_in[13];
    const float* b2     = (const float*)d_in[14];
    const float* g_in   = (const float*)d_in[15];
    const float* be_in  = (const float*)d_in[16];
    const float* g_sl   = (const float*)d_in[17];
    const float* be_sl  = (const float*)d_in[18];
    const float* g_ff   = (const float*)d_in[19];
    const float* be_ff  = (const float*)d_in[20];
    float* ws = (float*)d_ws;
    float* out = (float*)d_out;

    hipLaunchKernelGGL(k_transpose, dim3(24, 8, 5), dim3(256), 0, stream, W_ih, W_hh, Wv, W1, W2, ws);
    hipLaunchKernelGGL(k_m, dim3(256), dim3(256), 0, stream, Wq, Wk, ws);
    hipLaunchKernelGGL(k_init, dim3(512), dim3(256), 0, stream, mu, logsig, noise, ws);
    for (int it = 0; it < ITERS; ++it) {
        hipLaunchKernelGGL(k_qt, dim3(4, 64), dim3(256), 0, stream, ws, g_sl, be_sl);
        hipLaunchKernelGGL(k_attn, dim3(SEG, 64), dim3(64), 0, stream, x, g_in, be_in, ws);
        hipLaunchKernelGGL(k_upd, dim3(64), dim3(256), 0, stream, ws);
        hipLaunchKernelGGL(k_gru, dim3(8, 64), dim3(256), 0, stream, ws, b_ih, b_hh);
        hipLaunchKernelGGL(k_mlp1, dim3(4, 64), dim3(256), 0, stream, ws, g_ff, be_ff, b1);
        hipLaunchKernelGGL(k_mlp2, dim3(4, 64), dim3(256), 0, stream, ws, b2,
                           (it == ITERS - 1) ? out : nullptr);
    }
}

// Round 2
// 908.641 us; speedup vs baseline: 1.3195x; 1.3195x over previous
//
#include <hip/hip_runtime.h>
#include <cstddef>

#define DIM 256
#define NSLOT 8
#define BATCH 64
#define NTOK 4096
#define SEGB 16                 /* attn blocks per batch */
#define NPART SEGB              /* U/l partials per batch */
#define ITERS 3
#define EPS 1e-5f

typedef short bf16x8 __attribute__((ext_vector_type(8)));
typedef short bf16x4 __attribute__((ext_vector_type(4)));
typedef float f32x4  __attribute__((ext_vector_type(4)));

static __device__ __forceinline__ short f2bf(float f) {
    union { float f; unsigned u; } v; v.f = f;
    unsigned r = v.u + 0x7fffu + ((v.u >> 16) & 1u);   // RNE
    return (short)(r >> 16);
}

// ---------------- workspace layout (float offsets) ----------------
enum : size_t {
    OFF_M     = 0,                               // [256][256]  (Wq^T Wk) * d^-0.5
    OFF_WIHT  = OFF_M    + 256 * 256,            // [256][768]
    OFF_WHHT  = OFF_WIHT + 256 * 768,            // [256][768]
    OFF_WVT   = OFF_WHHT + 256 * 768,            // [256][256]
    OFF_W1T   = OFF_WVT  + 256 * 256,            // [256][256]
    OFF_W2T   = OFF_W1T  + 256 * 256,            // [256][256]
    OFF_SLOTS = OFF_W2T  + 256 * 256,            // [64][8][256]
    OFF_SNEW  = OFF_SLOTS + BATCH * NSLOT * 256, // [64][8][256]
    OFF_QT    = OFF_SNEW  + BATCH * NSLOT * 256, // [64][8][256]
    OFF_H     = OFF_QT    + BATCH * NSLOT * 256, // [64][8][256]
    OFF_UPD   = OFF_H     + BATCH * NSLOT * 256, // [64][8][256]
    OFF_UPART = OFF_UPD   + BATCH * NSLOT * 256, // [64][NPART][8][256]
    OFF_LPART = OFF_UPART + (size_t)BATCH * NPART * NSLOT * 256, // [64][NPART][16] (l:0-7, B1:8-15)
    WS_FLOATS = OFF_LPART + BATCH * NPART * 16
};

// ---------------- weight transposes (coalesced via LDS tile) ----------------
__global__ __launch_bounds__(256) void k_transpose(const float* __restrict__ w_ih,
                                                   const float* __restrict__ w_hh,
                                                   const float* __restrict__ wv,
                                                   const float* __restrict__ w1,
                                                   const float* __restrict__ w2,
                                                   float* __restrict__ ws) {
    int z = blockIdx.z;
    const float* src;
    float* dst;
    int R;
    if (z == 0)      { src = w_ih; dst = ws + OFF_WIHT; R = 768; }
    else if (z == 1) { src = w_hh; dst = ws + OFF_WHHT; R = 768; }
    else if (z == 2) { src = wv;   dst = ws + OFF_WVT;  R = 256; }
    else if (z == 3) { src = w1;   dst = ws + OFF_W1T;  R = 256; }
    else             { src = w2;   dst = ws + OFF_W2T;  R = 256; }
    if ((int)blockIdx.x * 32 >= R) return;
    __shared__ float tile[32][33];
    int lx = threadIdx.x & 31, ly = threadIdx.x >> 5;
    int r0 = blockIdx.x * 32, c0 = blockIdx.y * 32;
#pragma unroll
    for (int p = 0; p < 4; ++p)
        tile[ly + p * 8][lx] = src[(size_t)(r0 + ly + p * 8) * 256 + c0 + lx];
    __syncthreads();
#pragma unroll
    for (int p = 0; p < 4; ++p)
        dst[(size_t)(c0 + ly + p * 8) * R + r0 + lx] = tile[lx][ly + p * 8];
}

// ---------------- M = (Wq^T @ Wk) * d^-0.5 ----------------
__global__ __launch_bounds__(256) void k_m(const float* __restrict__ wq,
                                           const float* __restrict__ wk,
                                           float* __restrict__ ws) {
    int d = blockIdx.x, t = threadIdx.x;
    float acc = 0.f;
    for (int e = 0; e < 256; ++e)
        acc += wq[e * 256 + d] * wk[e * 256 + t];
    ws[OFF_M + d * 256 + t] = acc * 0.0625f; // 256^-0.5
}

// ---------------- slots init ----------------
__global__ __launch_bounds__(256) void k_init(const float* __restrict__ mu,
                                              const float* __restrict__ logsig,
                                              const float* __restrict__ noise,
                                              float* __restrict__ ws) {
    int i = blockIdx.x * 256 + threadIdx.x; // grid 512 -> 131072
    int d = i & 255;
    ws[OFF_SLOTS + i] = mu[d] + noise[i] * __expf(logsig[d]);
}

// ---------------- qt = LN(slots, g_sl) @ M ----------------
__global__ __launch_bounds__(256) void k_qt(float* __restrict__ ws,
                                            const float* __restrict__ g_sl,
                                            const float* __restrict__ be_sl) {
    __shared__ float ln[2048];
    int chunk = blockIdx.x, b = blockIdx.y;
    int t = threadIdx.x, wave = t >> 6, lane = t & 63;
    const float* slots = ws + OFF_SLOTS + b * 2048;
    float4 gf = ((const float4*)g_sl)[lane];
    float4 bf = ((const float4*)be_sl)[lane];
#pragma unroll
    for (int rr = 0; rr < 2; ++rr) {
        int r = wave + rr * 4;
        float4 v = ((const float4*)(slots + r * 256))[lane];
        float s1 = v.x + v.y + v.z + v.w;
        float s2 = v.x * v.x + v.y * v.y + v.z * v.z + v.w * v.w;
#pragma unroll
        for (int m = 1; m < 64; m <<= 1) { s1 += __shfl_xor(s1, m); s2 += __shfl_xor(s2, m); }
        float mu = s1 * (1.f / 256.f);
        float rstd = rsqrtf(s2 * (1.f / 256.f) - mu * mu + EPS);
        float4 o;
        o.x = (v.x - mu) * rstd * gf.x + bf.x;
        o.y = (v.y - mu) * rstd * gf.y + bf.y;
        o.z = (v.z - mu) * rstd * gf.z + bf.z;
        o.w = (v.w - mu) * rstd * gf.w + bf.w;
        *((float4*)&ln[r * 256 + lane * 4]) = o;
    }
    __syncthreads();
    const float* M = ws + OFF_M;
    int k0 = t >> 6;               // wave-uniform
    int e = chunk * 64 + (t & 63);
    float a0 = 0.f, a1 = 0.f;
    for (int d = 0; d < 256; ++d) {
        float m = M[d * 256 + e];
        a0 += ln[k0 * 256 + d] * m;
        a1 += ln[(k0 + 4) * 256 + d] * m;
    }
    float* qt = ws + OFF_QT + b * 2048;
    qt[k0 * 256 + e] = a0;
    qt[(k0 + 4) * 256 + e] = a1;
}

// ---------------- MFMA flash attention pass over x ----------------
// LN folded out: logit = rstd*S - mu*rstd*G[s] + C[s], with S = x_raw . (qt*g).
// U accumulated on raw x with rstd folded into E; B1[s] = sum E*mu*rstd correction.
// Verified-shape-only: mfma_f32_16x16x32_bf16.
__global__ __launch_bounds__(256) void k_attn(const float* __restrict__ x,
                                              const float* __restrict__ g_in,
                                              const float* __restrict__ be_in,
                                              float* __restrict__ ws) {
    int seg = blockIdx.x, b = blockIdx.y;
    int t = threadIdx.x;
    int w = t >> 6, lane = t & 63;
    int q = lane >> 4, s16 = lane & 15;

    __shared__ short qhi[16 * 264];      // (qt*g_in) bf16, rows 8-15 zero
    __shared__ short xT[256 * 64];       // bf16 raw-x transpose tile, XOR-swizzled groups
    __shared__ short Etmp[16 * 72];      // E*rstd bf16, [slot][token]
    __shared__ float GsL[16], CsL[16];
    __shared__ float lsum[4][8], b1sLDS[4][8];

    const float* qtg = ws + OFF_QT + b * 2048;

    // ---- build qhi = bf16(qt * g_in); zero slots 8-15 ----
    for (int idx = t; idx < 16 * 264; idx += 256) {
        int s = idx / 264, d = idx - s * 264;
        float v = (s < 8 && d < 256) ? qtg[s * 256 + d] * g_in[d] : 0.f;
        qhi[idx] = f2bf(v);
    }
    // ---- G[s] = sum qt*g, C[s] = sum qt*be (slots 0-7) ----
    {
        if (t >= 8 && t < 16) { GsL[t] = 0.f; CsL[t] = 0.f; }
        int s = t >> 5, j = t & 31;
        float pg = 0.f, pc = 0.f;
        for (int d = j; d < 256; d += 32) {
            float qv = qtg[s * 256 + d];
            pg += qv * g_in[d];
            pc += qv * be_in[d];
        }
#pragma unroll
        for (int m = 1; m < 32; m <<= 1) { pg += __shfl_xor(pg, m); pc += __shfl_xor(pc, m); }
        if (j == 0) { GsL[s] = pg; CsL[s] = pc; }
    }
    __syncthreads();

    // hoist qt B-frags: frag i holds (qt*g)[slot=s16][d = 32i + 8q .. +8]
    bf16x8 qf[8];
#pragma unroll
    for (int i = 0; i < 8; ++i)
        qf[i] = *(const bf16x8*)&qhi[s16 * 264 + i * 32 + q * 8];

    float Gv = GsL[s16], Cv = CsL[s16];

    f32x4 U[4];
#pragma unroll
    for (int c = 0; c < 4; ++c) U[c] = (f32x4){0.f, 0.f, 0.f, 0.f};
    float lacc = 0.f, b1acc = 0.f;

    const int tokens_per_block = NTOK / SEGB;        // 256
    const int tiles = tokens_per_block / 64;         // 4
    int mytok_base = seg * tokens_per_block + w * 16 + s16;
    int g0 = ((w * 16 + s16) >> 3);                  // token group within 64-tile
    int t7 = s16 & 7;

    for (int tt = 0; tt < tiles; ++tt) {
        // ---- load my token's row (raw x, fp32), chunk i covers d = 32i+8q..+8 ----
        const float* xr = x + ((size_t)b * NTOK + (size_t)(mytok_base + tt * 64)) * 256 + q * 8;
        const float4* xp = (const float4*)xr;
        float4 xa[8], xb[8];
#pragma unroll
        for (int i = 0; i < 8; ++i) { xa[i] = xp[8 * i]; xb[i] = xp[8 * i + 1]; }
        // ---- LN stats for my token (sum over q via 2 xor-shuffles) ----
        float s1 = 0.f, s2 = 0.f;
#pragma unroll
        for (int i = 0; i < 8; ++i) {
            s1 += xa[i].x + xa[i].y + xa[i].z + xa[i].w + xb[i].x + xb[i].y + xb[i].z + xb[i].w;
            s2 += xa[i].x * xa[i].x + xa[i].y * xa[i].y + xa[i].z * xa[i].z + xa[i].w * xa[i].w
                + xb[i].x * xb[i].x + xb[i].y * xb[i].y + xb[i].z * xb[i].z + xb[i].w * xb[i].w;
        }
        s1 += __shfl_xor(s1, 16); s2 += __shfl_xor(s2, 16);
        s1 += __shfl_xor(s1, 32); s2 += __shfl_xor(s2, 32);
        float mu = s1 * (1.f / 256.f);
        float rstd = rsqrtf(s2 * (1.f / 256.f) - mu * mu + EPS);

        // ---- bf16 frags of RAW x (A-operand for logits; also xT source) ----
        bf16x8 af[8];
#pragma unroll
        for (int i = 0; i < 8; ++i) {
            bf16x8 f;
            f[0] = f2bf(xa[i].x); f[1] = f2bf(xa[i].y); f[2] = f2bf(xa[i].z); f[3] = f2bf(xa[i].w);
            f[4] = f2bf(xb[i].x); f[5] = f2bf(xb[i].y); f[6] = f2bf(xb[i].z); f[7] = f2bf(xb[i].w);
            af[i] = f;
        }

        // ---- logits: S-tile via 8 MFMAs (A = my 16 tokens, B = qt*g) ----
        f32x4 Lc = (f32x4){0.f, 0.f, 0.f, 0.f};
#pragma unroll
        for (int i = 0; i < 8; ++i)
            Lc = __builtin_amdgcn_mfma_f32_16x16x32_bf16(af[i], qf[i], Lc, 0, 0, 0);

        // mu/rstd of the tokens this lane's C-regs refer to (token-local = q*4+r)
        float mur[4], rsr[4];
#pragma unroll
        for (int r = 0; r < 4; ++r) {
            mur[r] = __shfl(mu, q * 4 + r);
            rsr[r] = __shfl(rstd, q * 4 + r);
        }
        // finalize logits -> E (and E*rstd for the U-GEMM A-operand)
        bf16x4 e2;
#pragma unroll
        for (int r = 0; r < 4; ++r) {
            float logit = rsr[r] * Lc[r] - mur[r] * rsr[r] * Gv + Cv;
            float E = __expf(fminf(logit, 30.f));
            lacc += E;
            b1acc += E * mur[r] * rsr[r];
            e2[r] = f2bf(E * rsr[r]);
        }

        __syncthreads();   // (A) everyone done reading xT/Etmp of previous tile

        // ---- write transpose tile: xT[d][token], XOR-swizzled 8-token groups ----
#pragma unroll
        for (int i = 0; i < 8; ++i) {
            int Ki = (4 * i + q) & 7;
            int dbase = i * 32 + q * 8;
            bf16x8 f = af[i];
#pragma unroll
            for (int e = 0; e < 8; ++e) {
                int gp = (g0 ^ e ^ Ki) & 7;
                xT[((dbase + e) << 6) + (gp << 3) + t7] = f[e];
            }
        }
        // ---- write E*rstd: Etmp[slot=s16][token = 16w + q*4 .. +3] (one b64) ----
        *(bf16x4*)&Etmp[s16 * 72 + w * 16 + q * 4] = e2;

        __syncthreads();   // (B) xT + Etmp ready

        // ---- U-GEMM: my 4 d-chunks, K = 64 tokens (2 MFMA steps) ----
        bf16x8 ea0 = *(const bf16x8*)&Etmp[s16 * 72 + q * 8];
        bf16x8 ea1 = *(const bf16x8*)&Etmp[s16 * 72 + 32 + q * 8];
#pragma unroll
        for (int c = 0; c < 4; ++c) {
            int d = (4 * w + c) * 16 + s16;
            int swz = (d ^ (d >> 3)) & 7;
            const short* row = &xT[d << 6];
            bf16x8 b0 = *(const bf16x8*)&row[((q ^ swz) & 7) << 3];
            bf16x8 b1 = *(const bf16x8*)&row[(((4 + q) ^ swz) & 7) << 3];
            U[c] = __builtin_amdgcn_mfma_f32_16x16x32_bf16(ea0, b0, U[c], 0, 0, 0);
            U[c] = __builtin_amdgcn_mfma_f32_16x16x32_bf16(ea1, b1, U[c], 0, 0, 0);
        }
    }

    // ---- reduce l and B1 across quads, then waves; store partials ----
    lacc += __shfl_xor(lacc, 16); lacc += __shfl_xor(lacc, 32);
    b1acc += __shfl_xor(b1acc, 16); b1acc += __shfl_xor(b1acc, 32);
    __syncthreads();
    if (q == 0 && s16 < 8) { lsum[w][s16] = lacc; b1sLDS[w][s16] = b1acc; }
    __syncthreads();
    float* lpart = ws + OFF_LPART + (size_t)(b * NPART + seg) * 16;
    if (t < 8)  lpart[t] = lsum[0][t] + lsum[1][t] + lsum[2][t] + lsum[3][t];
    if (t >= 8 && t < 16) {
        int s = t - 8;
        lpart[8 + s] = b1sLDS[0][s] + b1sLDS[1][s] + b1sLDS[2][s] + b1sLDS[3][s];
    }
    // ---- store raw-U partial (slots 0-7; my d range = [64w, 64w+64)) ----
    float* up = ws + OFF_UPART + (size_t)(b * NPART + seg) * NSLOT * 256;
#pragma unroll
    for (int c = 0; c < 4; ++c) {
        int d = (4 * w + c) * 16 + s16;
#pragma unroll
        for (int r = 0; r < 4; ++r) {
            int slot = q * 4 + r;
            if (slot < 8) up[slot * 256 + d] = U[c][r];
        }
    }
}

// ---------------- combine partials, apply LN-fold correction, updates = u @ Wv^T ----------------
__global__ __launch_bounds__(256) void k_upd(float* __restrict__ ws,
                                             const float* __restrict__ g_in,
                                             const float* __restrict__ be_in) {
    __shared__ float uc[2048];
    __shared__ float lsv[8], b1v[8];
    int b = blockIdx.x, t = threadIdx.x;
    if (t < 8) {
        float ls = 0.f, b1 = 0.f;
        for (int g = 0; g < NPART; ++g) {
            ls += ws[OFF_LPART + (size_t)(b * NPART + g) * 16 + t];
            b1 += ws[OFF_LPART + (size_t)(b * NPART + g) * 16 + 8 + t];
        }
        lsv[t] = ls; b1v[t] = b1;
    }
    float acc[8] = {0.f, 0.f, 0.f, 0.f, 0.f, 0.f, 0.f, 0.f};
    const float* up0 = ws + OFF_UPART + (size_t)b * NPART * 8 * 256;
    for (int g = 0; g < NPART; ++g) {
        const float* up = up0 + g * 2048;
#pragma unroll
        for (int s = 0; s < 8; ++s) acc[s] += up[s * 256 + t];
    }
    __syncthreads();
    float gd = g_in[t], bd = be_in[t];
#pragma unroll
    for (int s = 0; s < 8; ++s) {
        // u = (g[d]*(Uraw - B1[s]) + be[d]*l[s]) / l[s]
        uc[s * 256 + t] = (gd * (acc[s] - b1v[s]) + bd * lsv[s]) / lsv[s];
    }
    __syncthreads();
    const float* WvT = ws + OFF_WVT;
    int k0 = t >> 6;   // wave-uniform
    int e0 = t & 63;
    float o0[4] = {0.f, 0.f, 0.f, 0.f};
    float o1[4] = {0.f, 0.f, 0.f, 0.f};
    for (int d = 0; d < 256; ++d) {
        float u0 = uc[k0 * 256 + d], u1 = uc[(k0 + 4) * 256 + d];
#pragma unroll
        for (int c = 0; c < 4; ++c) {
            float w = WvT[d * 256 + c * 64 + e0];
            o0[c] += u0 * w;
            o1[c] += u1 * w;
        }
    }
    float* updg = ws + OFF_UPD + b * 2048;
#pragma unroll
    for (int c = 0; c < 4; ++c) {
        updg[k0 * 256 + c * 64 + e0] = o0[c];
        updg[(k0 + 4) * 256 + c * 64 + e0] = o1[c];
    }
}

// ---------------- GRU cell ----------------
__global__ __launch_bounds__(256) void k_gru(float* __restrict__ ws,
                                             const float* __restrict__ b_ih,
                                             const float* __restrict__ b_hh) {
    __shared__ float upd[2048], sl[2048];
    int cg = blockIdx.x, b = blockIdx.y, t = threadIdx.x;
    const float* updg = ws + OFF_UPD + b * 2048;
    const float* slg = ws + OFF_SLOTS + b * 2048;
#pragma unroll
    for (int j = 0; j < 8; ++j) {
        upd[j * 256 + t] = updg[j * 256 + t];
        sl[j * 256 + t] = slg[j * 256 + t];
    }
    __syncthreads();
    int k = t >> 5, j = t & 31, c = cg * 32 + j;
    const float* WihT = ws + OFF_WIHT;
    const float* WhhT = ws + OFF_WHHT;
    float ar = 0.f, az = 0.f, an = 0.f, hr = 0.f, hz = 0.f, hn = 0.f;
    for (int d = 0; d < 256; ++d) {
        float ud = upd[k * 256 + d], sd = sl[k * 256 + d];
        const float* wi = WihT + d * 768;
        const float* wh = WhhT + d * 768;
        ar += ud * wi[c];       az += ud * wi[256 + c]; an += ud * wi[512 + c];
        hr += sd * wh[c];       hz += sd * wh[256 + c]; hn += sd * wh[512 + c];
    }
    float rg = 1.f / (1.f + __expf(-(ar + b_ih[c] + hr + b_hh[c])));
    float zg = 1.f / (1.f + __expf(-(az + b_ih[256 + c] + hz + b_hh[256 + c])));
    float ng = tanhf(an + b_ih[512 + c] + rg * (hn + b_hh[512 + c]));
    float hval = sl[k * 256 + c];
    ws[OFF_SNEW + b * 2048 + k * 256 + c] = (1.f - zg) * ng + zg * hval;
}

// ---------------- h = relu(LN(snew, g_ff) @ W1^T + b1) ----------------
__global__ __launch_bounds__(256) void k_mlp1(float* __restrict__ ws,
                                              const float* __restrict__ g_ff,
                                              const float* __restrict__ be_ff,
                                              const float* __restrict__ b1v) {
    __shared__ float ln[2048];
    int chunk = blockIdx.x, b = blockIdx.y;
    int t = threadIdx.x, wave = t >> 6, lane = t & 63;
    const float* sn = ws + OFF_SNEW + b * 2048;
    float4 gf = ((const float4*)g_ff)[lane];
    float4 bf = ((const float4*)be_ff)[lane];
#pragma unroll
    for (int rr = 0; rr < 2; ++rr) {
        int r = wave + rr * 4;
        float4 v = ((const float4*)(sn + r * 256))[lane];
        float s1 = v.x + v.y + v.z + v.w;
        float s2 = v.x * v.x + v.y * v.y + v.z * v.z + v.w * v.w;
#pragma unroll
        for (int m = 1; m < 64; m <<= 1) { s1 += __shfl_xor(s1, m); s2 += __shfl_xor(s2, m); }
        float mu = s1 * (1.f / 256.f);
        float rstd = rsqrtf(s2 * (1.f / 256.f) - mu * mu + EPS);
        float4 o;
        o.x = (v.x - mu) * rstd * gf.x + bf.x;
        o.y = (v.y - mu) * rstd * gf.y + bf.y;
        o.z = (v.z - mu) * rstd * gf.z + bf.z;
        o.w = (v.w - mu) * rstd * gf.w + bf.w;
        *((float4*)&ln[r * 256 + lane * 4]) = o;
    }
    __syncthreads();
    const float* W1T = ws + OFF_W1T;
    int k0 = t >> 6, e = chunk * 64 + (t & 63);
    float a0 = 0.f, a1 = 0.f;
    for (int d = 0; d < 256; ++d) {
        float w = W1T[d * 256 + e];
        a0 += ln[k0 * 256 + d] * w;
        a1 += ln[(k0 + 4) * 256 + d] * w;
    }
    float* h = ws + OFF_H + b * 2048;
    float bb = b1v[e];
    h[k0 * 256 + e] = fmaxf(a0 + bb, 0.f);
    h[(k0 + 4) * 256 + e] = fmaxf(a1 + bb, 0.f);
}

// ---------------- slots = snew + h @ W2^T + b2 (optionally -> out) ----------------
__global__ __launch_bounds__(256) void k_mlp2(float* __restrict__ ws,
                                              const float* __restrict__ b2v,
                                              float* __restrict__ dout) {
    __shared__ float hl[2048];
    int chunk = blockIdx.x, b = blockIdx.y, t = threadIdx.x;
    const float* h = ws + OFF_H + b * 2048;
#pragma unroll
    for (int j = 0; j < 8; ++j) hl[j * 256 + t] = h[j * 256 + t];
    __syncthreads();
    int k0 = t >> 6, e = chunk * 64 + (t & 63);
    const float* W2T = ws + OFF_W2T;
    float a0 = 0.f, a1 = 0.f;
    for (int d = 0; d < 256; ++d) {
        float w = W2T[d * 256 + e];
        a0 += hl[k0 * 256 + d] * w;
        a1 += hl[(k0 + 4) * 256 + d] * w;
    }
    const float* sn = ws + OFF_SNEW + b * 2048;
    float bb = b2v[e];
    float out0 = sn[k0 * 256 + e] + a0 + bb;
    float out1 = sn[(k0 + 4) * 256 + e] + a1 + bb;
    float* sl = ws + OFF_SLOTS + b * 2048;
    sl[k0 * 256 + e] = out0;
    sl[(k0 + 4) * 256 + e] = out1;
    if (dout) {
        dout[b * 2048 + k0 * 256 + e] = out0;
        dout[b * 2048 + (k0 + 4) * 256 + e] = out1;
    }
}

extern "C" void kernel_launch(void* const* d_in, const int* in_sizes, int n_in,
                              void* d_out, int out_size, void* d_ws, size_t ws_size,
                              hipStream_t stream) {
    const float* x      = (const float*)d_in[0];
    const float* noise  = (const float*)d_in[1];
    const float* mu     = (const float*)d_in[2];
    const float* logsig = (const float*)d_in[3];
    const float* Wq     = (const float*)d_in[4];
    const float* Wk     = (const float*)d_in[5];
    const float* Wv     = (const float*)d_in[6];
    const float* W_ih   = (const float*)d_in[7];
    const float* W_hh   = (const float*)d_in[8];
    const float* b_ih   = (const float*)d_in[9];
    const float* b_hh   = (const float*)d_in[10];
    const float* W1     = (const float*)d_in[11];
    const float* b1     = (const float*)d_in[12];
    const float* W2     = (const float*)d_in[13];
    const float* b2     = (const float*)d_in[14];
    const float* g_in   = (const float*)d_in[15];
    const float* be_in  = (const float*)d_in[16];
    const float* g_sl   = (const float*)d_in[17];
    const float* be_sl  = (const float*)d_in[18];
    const float* g_ff   = (const float*)d_in[19];
    const float* be_ff  = (const float*)d_in[20];
    float* ws = (float*)d_ws;
    float* out = (float*)d_out;

    hipLaunchKernelGGL(k_transpose, dim3(24, 8, 5), dim3(256), 0, stream, W_ih, W_hh, Wv, W1, W2, ws);
    hipLaunchKernelGGL(k_m, dim3(256), dim3(256), 0, stream, Wq, Wk, ws);
    hipLaunchKernelGGL(k_init, dim3(512), dim3(256), 0, stream, mu, logsig, noise, ws);
    for (int it = 0; it < ITERS; ++it) {
        hipLaunchKernelGGL(k_qt, dim3(4, 64), dim3(256), 0, stream, ws, g_sl, be_sl);
        hipLaunchKernelGGL(k_attn, dim3(SEGB, 64), dim3(256), 0, stream, x, g_in, be_in, ws);
        hipLaunchKernelGGL(k_upd, dim3(64), dim3(256), 0, stream, ws, g_in, be_in);
        hipLaunchKernelGGL(k_gru, dim3(8, 64), dim3(256), 0, stream, ws, b_ih, b_hh);
        hipLaunchKernelGGL(k_mlp1, dim3(4, 64), dim3(256), 0, stream, ws, g_ff, be_ff, b1);
        hipLaunchKernelGGL(k_mlp2, dim3(4, 64), dim3(256), 0, stream, ws, b2,
                           (it == ITERS - 1) ? out : nullptr);
    }
}